// Round 5
// baseline (452.026 us; speedup 1.0000x reference)
//
#include <hip/hip_runtime.h>
#include <cstdint>
#include <cstddef>

#define NE 16
#define TOPK 6
#define HID 1024
#define NTOK 8192
#define EPSF 1e-10f
#define CAP_ROWS 51200   // 400 mblocks * 128
#define MAXBLK 400

typedef short bf16x8 __attribute__((ext_vector_type(8)));
typedef float f32x4 __attribute__((ext_vector_type(4)));

__device__ __forceinline__ unsigned int f2bf_rne(float f) {
  union { float f; unsigned int u; } v;
  v.f = f;
  return (v.u + 0x7FFFu + ((v.u >> 16) & 1u)) >> 16;
}

__device__ __forceinline__ float bfbits2f(unsigned int hi16) {
  union { unsigned int u; float f; } v;
  v.u = hi16 << 16;
  return v.f;
}

__device__ __forceinline__ void load_lds16(const void* g, void* l) {
  __builtin_amdgcn_global_load_lds(
      (const __attribute__((address_space(1))) void*)g,
      (__attribute__((address_space(3))) void*)l, 16, 0, 0);
}

// router: 16 tokens/block (rw staged once, reused 16x), float4 dots.
// No global atomics. All lanes redundantly compute top-k; lanes 0..5 write
// g6, lane 32 writes pack+eps. Fuses X f32->bf16.
// gate_k = q_k/s_top (renorm and /acc cancel); eps = EPS*s/(s+EPS).
__global__ __launch_bounds__(256) void router_sparse_kernel(
    const float* __restrict__ tokens, const float* __restrict__ rw,
    const float* __restrict__ rb, unsigned short* __restrict__ Xb,
    unsigned int* __restrict__ topk, float* __restrict__ g6,
    float* __restrict__ epst) {
  __shared__ float s_rw[NE * HID];  // 64 KB
  const int tid = threadIdx.x;
  const int wv = tid >> 6;
  const int lane = tid & 63;

  for (int i = tid; i < NE * HID / 4; i += 256)
    ((float4*)s_rw)[i] = ((const float4*)rw)[i];
  __syncthreads();

  for (int ti = 0; ti < 4; ++ti) {
    const int token = blockIdx.x * 16 + wv * 4 + ti;
    const float* xp = tokens + (size_t)token * HID;

    // lane covers k = lane*4 + 256*c (c=0..3), float4 each
    float4 x4[4];
#pragma unroll
    for (int c = 0; c < 4; ++c)
      x4[c] = *(const float4*)(xp + lane * 4 + 256 * c);

    // fused bf16 convert (8B per lane per chunk, coalesced)
    unsigned short* xbrow = Xb + (size_t)token * HID;
#pragma unroll
    for (int c = 0; c < 4; ++c) {
      uint2 o;
      o.x = f2bf_rne(x4[c].x) | (f2bf_rne(x4[c].y) << 16);
      o.y = f2bf_rne(x4[c].z) | (f2bf_rne(x4[c].w) << 16);
      *(uint2*)(xbrow + lane * 4 + 256 * c) = o;
    }

    float lg[NE];
#pragma unroll
    for (int e = 0; e < NE; ++e) {
      const float4* w4 = (const float4*)(s_rw + e * HID);
      float p = 0.f;
#pragma unroll
      for (int c = 0; c < 4; ++c) {
        const float4 w = w4[lane + 64 * c];
        p += x4[c].x * w.x + x4[c].y * w.y + x4[c].z * w.z + x4[c].w * w.w;
      }
      lg[e] = p;
    }
#pragma unroll
    for (int m = 1; m < 64; m <<= 1) {
#pragma unroll
      for (int e = 0; e < NE; ++e) lg[e] += __shfl_xor(lg[e], m);
    }
    float mx = -1e30f;
#pragma unroll
    for (int e = 0; e < NE; ++e) {
      lg[e] += rb[e];
      mx = fmaxf(mx, lg[e]);
    }
    float q[NE];
    float s_all = 0.f;
#pragma unroll
    for (int e = 0; e < NE; ++e) {
      q[e] = expf(lg[e] - mx);
      s_all += q[e];
    }
    unsigned sel = 0, pack = 0;
    float s_top = 0.f;
    float gq[TOPK];
#pragma unroll
    for (int k = 0; k < TOPK; ++k) {
      float best = -1.f;
      int bi = 0;
#pragma unroll
      for (int e = 0; e < NE; ++e) {
        bool taken = (sel >> e) & 1u;
        if (!taken && q[e] > best) { best = q[e]; bi = e; }
      }
      sel |= 1u << bi;
      gq[k] = best;
      s_top += best;
      pack |= ((unsigned)bi) << (4 * k);
    }
    if (lane < TOPK)
      g6[(size_t)token * TOPK + lane] = gq[lane] / s_top;
    if (lane == 32) {
      topk[token] = pack;
      float s = s_top / s_all;
      epst[token] = EPSF * (s / (s + EPSF));
    }
  }
}

// merged hist + scan + rank-scatter + pad-fill. One block per expert.
// Coalesced topk reads (t = i*256+tid); rank order is a deterministic
// permutation (output invariant to within-expert order). Packed u64 byte
// counters -> 16 LDS atomics/thread. No global atomics.
__global__ __launch_bounds__(256) void sortassign_kernel(
    const unsigned int* __restrict__ topk, const float* __restrict__ g6,
    unsigned int* __restrict__ tokmap, float* __restrict__ gpos,
    unsigned int* __restrict__ inv, unsigned int* __restrict__ table,
    unsigned int* __restrict__ total) {
  __shared__ unsigned int hist[NE];
  __shared__ unsigned int s_seg[NE];
  __shared__ unsigned int s_sc[256];
  const int e = blockIdx.x;
  const int tid = threadIdx.x;

  if (tid < NE) hist[tid] = 0;
  __syncthreads();

  unsigned long long clo = 0ull, chi = 0ull;
  for (int i = 0; i < NTOK / 256; ++i) {
    const unsigned p = topk[i * 256 + tid];
#pragma unroll
    for (int k = 0; k < TOPK; ++k) {
      const unsigned nib = (p >> (4 * k)) & 15u;
      if (nib < 8) clo += 1ull << (8 * nib);
      else chi += 1ull << (8 * (nib - 8));
    }
  }
#pragma unroll
  for (int j = 0; j < 8; ++j) {
    unsigned v = (unsigned)((clo >> (8 * j)) & 255u);
    if (v) atomicAdd(&hist[j], v);
    v = (unsigned)((chi >> (8 * j)) & 255u);
    if (v) atomicAdd(&hist[8 + j], v);
  }
  __syncthreads();
  if (tid == 0) {
    unsigned off = 0;
    for (int i = 0; i < NE; ++i) {
      s_seg[i] = off;
      off += ((hist[i] + 127) >> 7) << 7;
    }
  }
  __syncthreads();
  if (e == 0 && tid == 0) {
    unsigned b = 0;
    for (int i = 0; i < NE; ++i) {
      unsigned mb = (hist[i] + 127) >> 7;
      for (unsigned m = 0; m < mb; ++m)
        table[b++] = ((unsigned)i << 24) | (s_seg[i] + m * 128);
    }
    *total = b;
  }

  const unsigned c =
      (unsigned)(((e < 8 ? (clo >> (8 * e)) : (chi >> (8 * (e - 8))))) & 255u);
  s_sc[tid] = c;
  __syncthreads();
  for (int off = 1; off < 256; off <<= 1) {
    unsigned v = (tid >= off) ? s_sc[tid - off] : 0u;
    __syncthreads();
    s_sc[tid] += v;
    __syncthreads();
  }
  const unsigned seg0 = s_seg[e];
  unsigned pos = seg0 + s_sc[tid] - c;
  for (int i = 0; i < NTOK / 256; ++i) {
    const int t = i * 256 + tid;
    const unsigned p = topk[t];
#pragma unroll
    for (int k = 0; k < TOPK; ++k) {
      if (((p >> (4 * k)) & 15u) == (unsigned)e) {
        tokmap[pos] = (unsigned)t;
        gpos[pos] = g6[(size_t)t * TOPK + k];
        inv[(size_t)t * TOPK + k] = pos;
        ++pos;
      }
    }
  }
  const unsigned cnt_e = s_sc[255];
  const unsigned segend = seg0 + (((cnt_e + 127) >> 7) << 7);
  for (unsigned p2 = seg0 + cnt_e + tid; p2 < segend; p2 += 256) {
    tokmap[p2] = 0u;
    gpos[p2] = 0.f;
  }
}

// W fp32 [e][k][n] -> bf16 transposed [e][n][k]; vectorized u32 stores.
__global__ __launch_bounds__(256) void cvt_wt_kernel(
    const float* __restrict__ w, unsigned short* __restrict__ wt) {
  __shared__ float tile[64][65];
  const int kt = blockIdx.x * 64;
  const int nt = blockIdx.y * 64;
  const int e = blockIdx.z;
  const int tr = threadIdx.x >> 6;
  const int tc = threadIdx.x & 63;
  const float* wp = w + (size_t)e * HID * HID;
#pragma unroll
  for (int r = 0; r < 64; r += 4)
    tile[r + tr][tc] = wp[(size_t)(kt + r + tr) * HID + nt + tc];
  __syncthreads();
  unsigned short* wo = wt + (size_t)e * HID * HID;
  const int a = threadIdx.x & 31;   // k-pair index
  const int rg = threadIdx.x >> 5;  // row-in-group 0..7
#pragma unroll
  for (int c = 0; c < 64; c += 8) {
    const int n = c + rg;
    const unsigned lo = f2bf_rne(tile[2 * a][n]);
    const unsigned hi = f2bf_rne(tile[2 * a + 1][n]);
    *(unsigned int*)(wo + (size_t)(nt + n) * HID + kt + 2 * a) = lo | (hi << 16);
  }
}

// grouped GEMM, BK=64 (two 32-k half-buffers in the proven 64B-row layout;
// halves the barrier count vs BK=32). 1-D swizzled grid: n0=(bx&7)*128.
// Y[row,n] = gate[row] * (X[tok[row],:] @ We[:,n]), bf16 out.
__global__ __launch_bounds__(256, 4) void moe_ggemm_kernel(
    const unsigned short* __restrict__ Xb, const unsigned short* __restrict__ Wt,
    const unsigned int* __restrict__ table, const unsigned int* __restrict__ total,
    const unsigned int* __restrict__ tokmap, const float* __restrict__ gpos,
    unsigned short* __restrict__ Y) {
  __shared__ unsigned short As[2][128 * 32];  // [half][row][k] 64B rows
  __shared__ unsigned short Bs[2][128 * 32];
  __shared__ unsigned int Ts[128];
  __shared__ float Gs[128];

  const unsigned tot = *total;
  const unsigned bx = blockIdx.x;
  const unsigned slot = bx >> 3;
  if (slot >= tot) return;
  const int n0 = (bx & 7) * 128;
  const unsigned ent = table[slot];
  const int e = ent >> 24;
  const int row0 = ent & 0xFFFFFF;

  const int tid = threadIdx.x;
  const int wv = tid >> 6;
  const int lane = tid & 63;
  const int lm = lane & 15;
  const int quad = lane >> 4;
  const int woff_m = (wv & 1) * 64;
  const int woff_n = (wv >> 1) * 64;

  if (tid < 128) {
    Ts[tid] = tokmap[row0 + tid];
    Gs[tid] = gpos[row0 + tid];
  }
  __syncthreads();

  const int srow = wv * 32 + (lane >> 2);
  const int schunk = (lane & 3) * 16;
  // A: two gathered rows per lane (issues j=0,1), two k-halves each
  const char* gA0 = (const char*)Xb + (size_t)Ts[srow] * (HID * 2) + schunk;
  const char* gA1 = (const char*)Xb + (size_t)Ts[srow + 16] * (HID * 2) + schunk;
  const char* gB0 = (const char*)Wt + (size_t)e * (HID * HID * 2) +
                    (size_t)(n0 + srow) * (HID * 2) + schunk;
  const char* gB1 = gB0 + 16 * HID * 2;
  char* const lA0 = (char*)As + (wv * 32) * 64;
  char* const lA1 = lA0 + 16 * 64;
  char* const lB0 = (char*)Bs + (wv * 32) * 64;
  char* const lB1 = lB0 + 16 * 64;
  const int HB = 128 * 32 * 2;  // bytes per half-buffer

  f32x4 acc[4][4];
#pragma unroll
  for (int i = 0; i < 4; ++i)
#pragma unroll
    for (int j = 0; j < 4; ++j) acc[i][j] = (f32x4){0.f, 0.f, 0.f, 0.f};

  for (int ks = 0; ks < 16; ++ks) {
    __syncthreads();
    // half 0 (k-bytes +0..63), half 1 (+64..127)
    load_lds16(gA0, lA0);
    load_lds16(gA1, lA1);
    load_lds16(gA0 + 64, lA0 + HB);
    load_lds16(gA1 + 64, lA1 + HB);
    load_lds16(gB0, lB0);
    load_lds16(gB1, lB1);
    load_lds16(gB0 + 64, lB0 + HB);
    load_lds16(gB1 + 64, lB1 + HB);
    gA0 += 128; gA1 += 128; gB0 += 128; gB1 += 128;
    __syncthreads();

#pragma unroll
    for (int kh = 0; kh < 2; ++kh) {
      bf16x8 a[4], b[4];
#pragma unroll
      for (int i = 0; i < 4; ++i)
        a[i] = *(const bf16x8*)((const char*)As + kh * HB +
                                (woff_m + 16 * i + lm) * 64 + quad * 16);
#pragma unroll
      for (int j = 0; j < 4; ++j)
        b[j] = *(const bf16x8*)((const char*)Bs + kh * HB +
                                (woff_n + 16 * j + lm) * 64 + quad * 16);
#pragma unroll
      for (int i = 0; i < 4; ++i)
#pragma unroll
        for (int j = 0; j < 4; ++j)
          acc[i][j] =
              __builtin_amdgcn_mfma_f32_16x16x32_bf16(a[i], b[j], acc[i][j], 0, 0, 0);
    }
  }

#pragma unroll
  for (int i = 0; i < 4; ++i)
#pragma unroll
    for (int r = 0; r < 4; ++r) {
      const int row = woff_m + 16 * i + quad * 4 + r;
      const float g = Gs[row];
      unsigned short* yrow = Y + (size_t)(row0 + row) * HID + n0;
#pragma unroll
      for (int j = 0; j < 4; ++j)
        yrow[woff_n + 16 * j + lm] = (unsigned short)f2bf_rne(g * acc[i][j][r]);
    }
}

// reduce: out[t,:] = sum_k Y[inv[t,k],:] + eps[t].  2 tokens/block.
__global__ __launch_bounds__(256) void reduce_kernel(
    const unsigned short* __restrict__ Y, const unsigned int* __restrict__ inv,
    const float* __restrict__ epst, float* __restrict__ out) {
  const int sub = threadIdx.x >> 7;
  const int ct = threadIdx.x & 127;
  const int t = blockIdx.x * 2 + sub;
  const int c0 = ct * 8;

  float s[8];
  const float ep = epst[t];
#pragma unroll
  for (int i = 0; i < 8; ++i) s[i] = ep;

#pragma unroll
  for (int k = 0; k < TOPK; ++k) {
    const unsigned pos = inv[(size_t)t * TOPK + k];
    const uint4 v = *(const uint4*)(Y + (size_t)pos * HID + c0);
    s[0] += bfbits2f(v.x & 0xFFFFu);
    s[1] += bfbits2f(v.x >> 16);
    s[2] += bfbits2f(v.y & 0xFFFFu);
    s[3] += bfbits2f(v.y >> 16);
    s[4] += bfbits2f(v.z & 0xFFFFu);
    s[5] += bfbits2f(v.z >> 16);
    s[6] += bfbits2f(v.w & 0xFFFFu);
    s[7] += bfbits2f(v.w >> 16);
  }
  float* orow = out + (size_t)t * HID + c0;
  *(float4*)orow = (float4){s[0], s[1], s[2], s[3]};
  *(float4*)(orow + 4) = (float4){s[4], s[5], s[6], s[7]};
}

extern "C" void kernel_launch(void* const* d_in, const int* in_sizes, int n_in,
                              void* d_out, int out_size, void* d_ws, size_t ws_size,
                              hipStream_t stream) {
  const float* tokens = (const float*)d_in[0];  // [4,2048,1024] f32
  const float* rw = (const float*)d_in[1];      // [16,1024] f32
  const float* rb = (const float*)d_in[2];      // [16] f32
  const float* ew = (const float*)d_in[3];      // [16,1024,1024] f32
  float* out = (float*)d_out;                   // [4,2048,1024] f32

  char* ws = (char*)d_ws;
  const size_t OFF_XB = 0;                        // 16 MB
  const size_t OFF_WT = 16777216;                 // 32 MB
  const size_t OFF_Y = 50331648;                  // 100 MB (51200 x 1024 bf16)
  const size_t OFF_META = 155189248;
  const size_t M_TOKMAP = OFF_META + 0;           // 51200 u32
  const size_t M_GPOS = OFF_META + 204800;        // 51200 f32
  const size_t M_TOTAL = OFF_META + 409600;       // 1 u32 (pad 64)
  const size_t M_TABLE = OFF_META + 409664;       // 400 u32 (pad)
  const size_t M_INV = OFF_META + 411328;         // 49152 u32
  const size_t M_TOPK = OFF_META + 607936;        // 8192 u32
  const size_t M_G6 = OFF_META + 640704;          // 49152 f32
  const size_t M_EPST = OFF_META + 837312;        // 8192 f32

  unsigned short* Xb = (unsigned short*)(ws + OFF_XB);
  unsigned short* Wt = (unsigned short*)(ws + OFF_WT);
  unsigned short* Y = (unsigned short*)(ws + OFF_Y);
  unsigned int* tokmap = (unsigned int*)(ws + M_TOKMAP);
  float* gpos = (float*)(ws + M_GPOS);
  unsigned int* total = (unsigned int*)(ws + M_TOTAL);
  unsigned int* table = (unsigned int*)(ws + M_TABLE);
  unsigned int* inv = (unsigned int*)(ws + M_INV);
  unsigned int* topk = (unsigned int*)(ws + M_TOPK);
  float* g6 = (float*)(ws + M_G6);
  float* epst = (float*)(ws + M_EPST);

  router_sparse_kernel<<<dim3(NTOK / 16), dim3(256), 0, stream>>>(
      tokens, rw, rb, Xb, topk, g6, epst);
  cvt_wt_kernel<<<dim3(HID / 64, HID / 64, NE), dim3(256), 0, stream>>>(ew, Wt);
  sortassign_kernel<<<dim3(NE), dim3(256), 0, stream>>>(
      topk, g6, tokmap, gpos, inv, table, total);
  moe_ggemm_kernel<<<dim3(MAXBLK * 8), dim3(256), 0, stream>>>(
      Xb, Wt, table, total, tokmap, gpos, Y);
  reduce_kernel<<<dim3(NTOK / 2), dim3(256), 0, stream>>>(Y, inv, epst, out);
}

// Round 6
// 449.045 us; speedup vs baseline: 1.0066x; 1.0066x over previous
//
#include <hip/hip_runtime.h>
#include <cstdint>
#include <cstddef>

#define NE 16
#define TOPK 6
#define HID 1024
#define NTOK 8192
#define EPSF 1e-10f
#define CAP_ROWS 51200   // 400 mblocks * 128
#define MAXBLK 400
#define TRASH_ROW (NTOK * TOPK)  // 49152: pad rows dump here (value unused)

typedef short bf16x8 __attribute__((ext_vector_type(8)));
typedef float f32x4 __attribute__((ext_vector_type(4)));

__device__ __forceinline__ unsigned int f2bf_rne(float f) {
  union { float f; unsigned int u; } v;
  v.f = f;
  return (v.u + 0x7FFFu + ((v.u >> 16) & 1u)) >> 16;
}

__device__ __forceinline__ float bfbits2f(unsigned int hi16) {
  union { unsigned int u; float f; } v;
  v.u = hi16 << 16;
  return v.f;
}

__device__ __forceinline__ void load_lds16(const void* g, void* l) {
  __builtin_amdgcn_global_load_lds(
      (const __attribute__((address_space(1))) void*)g,
      (__attribute__((address_space(3))) void*)l, 16, 0, 0);
}

// router: 1 token/wave (grid 2048 -- round-5's 4-serial-tokens/wave halved
// wave parallelism and regressed 60us), float4 loads, fused X f32->bf16.
// No global atomics. All lanes redundantly compute top-k.
// gate_k = q_k/s_top (renorm and /acc cancel); eps = EPS*s/(s+EPS).
__global__ __launch_bounds__(256) void router_sparse_kernel(
    const float* __restrict__ tokens, const float* __restrict__ rw,
    const float* __restrict__ rb, unsigned short* __restrict__ Xb,
    unsigned int* __restrict__ topk, float* __restrict__ g6,
    float* __restrict__ epst) {
  __shared__ float s_rw[NE * HID];  // 64 KB
  const int tid = threadIdx.x;
  const int wv = tid >> 6;
  const int lane = tid & 63;
  const int token = blockIdx.x * 4 + wv;

  for (int i = tid; i < NE * HID / 4; i += 256)
    ((float4*)s_rw)[i] = ((const float4*)rw)[i];
  __syncthreads();

  const float* xp = tokens + (size_t)token * HID;
  float4 x4[4];
#pragma unroll
  for (int c = 0; c < 4; ++c)
    x4[c] = *(const float4*)(xp + lane * 4 + 256 * c);

  unsigned short* xbrow = Xb + (size_t)token * HID;
#pragma unroll
  for (int c = 0; c < 4; ++c) {
    uint2 o;
    o.x = f2bf_rne(x4[c].x) | (f2bf_rne(x4[c].y) << 16);
    o.y = f2bf_rne(x4[c].z) | (f2bf_rne(x4[c].w) << 16);
    *(uint2*)(xbrow + lane * 4 + 256 * c) = o;
  }

  float lg[NE];
#pragma unroll
  for (int e = 0; e < NE; ++e) {
    const float4* w4 = (const float4*)(s_rw + e * HID);
    float p = 0.f;
#pragma unroll
    for (int c = 0; c < 4; ++c) {
      const float4 w = w4[lane + 64 * c];
      p += x4[c].x * w.x + x4[c].y * w.y + x4[c].z * w.z + x4[c].w * w.w;
    }
    lg[e] = p;
  }
#pragma unroll
  for (int m = 1; m < 64; m <<= 1) {
#pragma unroll
    for (int e = 0; e < NE; ++e) lg[e] += __shfl_xor(lg[e], m);
  }
  float mx = -1e30f;
#pragma unroll
  for (int e = 0; e < NE; ++e) {
    lg[e] += rb[e];
    mx = fmaxf(mx, lg[e]);
  }
  float q[NE];
  float s_all = 0.f;
#pragma unroll
  for (int e = 0; e < NE; ++e) {
    q[e] = expf(lg[e] - mx);
    s_all += q[e];
  }
  unsigned sel = 0, pack = 0;
  float s_top = 0.f;
  float gq[TOPK];
#pragma unroll
  for (int k = 0; k < TOPK; ++k) {
    float best = -1.f;
    int bi = 0;
#pragma unroll
    for (int e = 0; e < NE; ++e) {
      bool taken = (sel >> e) & 1u;
      if (!taken && q[e] > best) { best = q[e]; bi = e; }
    }
    sel |= 1u << bi;
    gq[k] = best;
    s_top += best;
    pack |= ((unsigned)bi) << (4 * k);
  }
  if (lane < TOPK)
    g6[(size_t)token * TOPK + lane] = gq[lane] / s_top;
  if (lane == 32) {
    topk[token] = pack;
    float s = s_top / s_all;
    epst[token] = EPSF * (s / (s + EPSF));
  }
}

// merged hist + scan + rank-scatter + pad-fill. One block per expert.
// Coalesced topk reads; packed u64 byte counters -> 16 LDS atomics/thread.
// Emits ydst[pos] = t*6+k (token-major Y row) instead of inv.
__global__ __launch_bounds__(256) void sortassign_kernel(
    const unsigned int* __restrict__ topk, const float* __restrict__ g6,
    unsigned int* __restrict__ tokmap, float* __restrict__ gpos,
    unsigned int* __restrict__ ydst, unsigned int* __restrict__ table,
    unsigned int* __restrict__ total) {
  __shared__ unsigned int hist[NE];
  __shared__ unsigned int s_seg[NE];
  __shared__ unsigned int s_sc[256];
  const int e = blockIdx.x;
  const int tid = threadIdx.x;

  if (tid < NE) hist[tid] = 0;
  __syncthreads();

  unsigned long long clo = 0ull, chi = 0ull;
  for (int i = 0; i < NTOK / 256; ++i) {
    const unsigned p = topk[i * 256 + tid];
#pragma unroll
    for (int k = 0; k < TOPK; ++k) {
      const unsigned nib = (p >> (4 * k)) & 15u;
      if (nib < 8) clo += 1ull << (8 * nib);
      else chi += 1ull << (8 * (nib - 8));
    }
  }
#pragma unroll
  for (int j = 0; j < 8; ++j) {
    unsigned v = (unsigned)((clo >> (8 * j)) & 255u);
    if (v) atomicAdd(&hist[j], v);
    v = (unsigned)((chi >> (8 * j)) & 255u);
    if (v) atomicAdd(&hist[8 + j], v);
  }
  __syncthreads();
  if (tid == 0) {
    unsigned off = 0;
    for (int i = 0; i < NE; ++i) {
      s_seg[i] = off;
      off += ((hist[i] + 127) >> 7) << 7;
    }
  }
  __syncthreads();
  if (e == 0 && tid == 0) {
    unsigned b = 0;
    for (int i = 0; i < NE; ++i) {
      unsigned mb = (hist[i] + 127) >> 7;
      for (unsigned m = 0; m < mb; ++m)
        table[b++] = ((unsigned)i << 24) | (s_seg[i] + m * 128);
    }
    *total = b;
  }

  const unsigned c =
      (unsigned)(((e < 8 ? (clo >> (8 * e)) : (chi >> (8 * (e - 8))))) & 255u);
  s_sc[tid] = c;
  __syncthreads();
  for (int off = 1; off < 256; off <<= 1) {
    unsigned v = (tid >= off) ? s_sc[tid - off] : 0u;
    __syncthreads();
    s_sc[tid] += v;
    __syncthreads();
  }
  const unsigned seg0 = s_seg[e];
  unsigned pos = seg0 + s_sc[tid] - c;
  for (int i = 0; i < NTOK / 256; ++i) {
    const int t = i * 256 + tid;
    const unsigned p = topk[t];
#pragma unroll
    for (int k = 0; k < TOPK; ++k) {
      if (((p >> (4 * k)) & 15u) == (unsigned)e) {
        tokmap[pos] = (unsigned)t;
        gpos[pos] = g6[(size_t)t * TOPK + k];
        ydst[pos] = (unsigned)(t * TOPK + k);
        ++pos;
      }
    }
  }
  const unsigned cnt_e = s_sc[255];
  const unsigned segend = seg0 + (((cnt_e + 127) >> 7) << 7);
  for (unsigned p2 = seg0 + cnt_e + tid; p2 < segend; p2 += 256) {
    tokmap[p2] = 0u;
    gpos[p2] = 0.f;
    ydst[p2] = TRASH_ROW;
  }
}

// W fp32 [e][k][n] -> bf16 transposed [e][n][k]; vectorized u32 stores.
__global__ __launch_bounds__(256) void cvt_wt_kernel(
    const float* __restrict__ w, unsigned short* __restrict__ wt) {
  __shared__ float tile[64][65];
  const int kt = blockIdx.x * 64;
  const int nt = blockIdx.y * 64;
  const int e = blockIdx.z;
  const int tr = threadIdx.x >> 6;
  const int tc = threadIdx.x & 63;
  const float* wp = w + (size_t)e * HID * HID;
#pragma unroll
  for (int r = 0; r < 64; r += 4)
    tile[r + tr][tc] = wp[(size_t)(kt + r + tr) * HID + nt + tc];
  __syncthreads();
  unsigned short* wo = wt + (size_t)e * HID * HID;
  const int a = threadIdx.x & 31;   // k-pair index
  const int rg = threadIdx.x >> 5;  // row-in-group 0..7
#pragma unroll
  for (int c = 0; c < 64; c += 8) {
    const int n = c + rg;
    const unsigned lo = f2bf_rne(tile[2 * a][n]);
    const unsigned hi = f2bf_rne(tile[2 * a + 1][n]);
    *(unsigned int*)(wo + (size_t)(nt + n) * HID + kt + 2 * a) = lo | (hi << 16);
  }
}

// grouped GEMM, BK=64 half-buffers, 1-D swizzled grid n0=(bx&7)*128.
// Y[ydst[row], n] = gate[row] * (X[tok[row],:] @ We[:,n]), bf16, token-major
// scatter (reduce then streams sequentially).
__global__ __launch_bounds__(256, 4) void moe_ggemm_kernel(
    const unsigned short* __restrict__ Xb, const unsigned short* __restrict__ Wt,
    const unsigned int* __restrict__ table, const unsigned int* __restrict__ total,
    const unsigned int* __restrict__ tokmap, const float* __restrict__ gpos,
    const unsigned int* __restrict__ ydst, unsigned short* __restrict__ Y) {
  __shared__ unsigned short As[2][128 * 32];  // [half][row][k] 64B rows
  __shared__ unsigned short Bs[2][128 * 32];
  __shared__ unsigned int Ts[128];
  __shared__ float Gs[128];
  __shared__ unsigned int Ys[128];

  const unsigned tot = *total;
  const unsigned bx = blockIdx.x;
  const unsigned slot = bx >> 3;
  if (slot >= tot) return;
  const int n0 = (bx & 7) * 128;
  const unsigned ent = table[slot];
  const int e = ent >> 24;
  const int row0 = ent & 0xFFFFFF;

  const int tid = threadIdx.x;
  const int wv = tid >> 6;
  const int lane = tid & 63;
  const int lm = lane & 15;
  const int quad = lane >> 4;
  const int woff_m = (wv & 1) * 64;
  const int woff_n = (wv >> 1) * 64;

  if (tid < 128) {
    Ts[tid] = tokmap[row0 + tid];
    Gs[tid] = gpos[row0 + tid];
    Ys[tid] = ydst[row0 + tid];
  }
  __syncthreads();

  const int srow = wv * 32 + (lane >> 2);
  const int schunk = (lane & 3) * 16;
  const char* gA0 = (const char*)Xb + (size_t)Ts[srow] * (HID * 2) + schunk;
  const char* gA1 = (const char*)Xb + (size_t)Ts[srow + 16] * (HID * 2) + schunk;
  const char* gB0 = (const char*)Wt + (size_t)e * (HID * HID * 2) +
                    (size_t)(n0 + srow) * (HID * 2) + schunk;
  const char* gB1 = gB0 + 16 * HID * 2;
  char* const lA0 = (char*)As + (wv * 32) * 64;
  char* const lA1 = lA0 + 16 * 64;
  char* const lB0 = (char*)Bs + (wv * 32) * 64;
  char* const lB1 = lB0 + 16 * 64;
  const int HB = 128 * 32 * 2;  // bytes per half-buffer

  f32x4 acc[4][4];
#pragma unroll
  for (int i = 0; i < 4; ++i)
#pragma unroll
    for (int j = 0; j < 4; ++j) acc[i][j] = (f32x4){0.f, 0.f, 0.f, 0.f};

  for (int ks = 0; ks < 16; ++ks) {
    __syncthreads();
    load_lds16(gA0, lA0);
    load_lds16(gA1, lA1);
    load_lds16(gA0 + 64, lA0 + HB);
    load_lds16(gA1 + 64, lA1 + HB);
    load_lds16(gB0, lB0);
    load_lds16(gB1, lB1);
    load_lds16(gB0 + 64, lB0 + HB);
    load_lds16(gB1 + 64, lB1 + HB);
    gA0 += 128; gA1 += 128; gB0 += 128; gB1 += 128;
    __syncthreads();

#pragma unroll
    for (int kh = 0; kh < 2; ++kh) {
      bf16x8 a[4], b[4];
#pragma unroll
      for (int i = 0; i < 4; ++i)
        a[i] = *(const bf16x8*)((const char*)As + kh * HB +
                                (woff_m + 16 * i + lm) * 64 + quad * 16);
#pragma unroll
      for (int j = 0; j < 4; ++j)
        b[j] = *(const bf16x8*)((const char*)Bs + kh * HB +
                                (woff_n + 16 * j + lm) * 64 + quad * 16);
#pragma unroll
      for (int i = 0; i < 4; ++i)
#pragma unroll
        for (int j = 0; j < 4; ++j)
          acc[i][j] =
              __builtin_amdgcn_mfma_f32_16x16x32_bf16(a[i], b[j], acc[i][j], 0, 0, 0);
    }
  }

#pragma unroll
  for (int i = 0; i < 4; ++i)
#pragma unroll
    for (int r = 0; r < 4; ++r) {
      const int row = woff_m + 16 * i + quad * 4 + r;
      const float g = Gs[row];
      unsigned short* yrow = Y + (size_t)Ys[row] * HID + n0;
#pragma unroll
      for (int j = 0; j < 4; ++j)
        yrow[woff_n + 16 * j + lm] = (unsigned short)f2bf_rne(g * acc[i][j][r]);
    }
}

// reduce: out[t,:] = sum_k Y[t*6+k,:] + eps[t]. Fully sequential reads
// (12 KB/token), no indirection. 2 tokens/block.
__global__ __launch_bounds__(256) void reduce_kernel(
    const unsigned short* __restrict__ Y, const float* __restrict__ epst,
    float* __restrict__ out) {
  const int sub = threadIdx.x >> 7;
  const int ct = threadIdx.x & 127;
  const int t = blockIdx.x * 2 + sub;
  const int c0 = ct * 8;

  float s[8];
  const float ep = epst[t];
#pragma unroll
  for (int i = 0; i < 8; ++i) s[i] = ep;

  const unsigned short* ybase = Y + (size_t)t * TOPK * HID + c0;
#pragma unroll
  for (int k = 0; k < TOPK; ++k) {
    const uint4 v = *(const uint4*)(ybase + k * HID);
    s[0] += bfbits2f(v.x & 0xFFFFu);
    s[1] += bfbits2f(v.x >> 16);
    s[2] += bfbits2f(v.y & 0xFFFFu);
    s[3] += bfbits2f(v.y >> 16);
    s[4] += bfbits2f(v.z & 0xFFFFu);
    s[5] += bfbits2f(v.z >> 16);
    s[6] += bfbits2f(v.w & 0xFFFFu);
    s[7] += bfbits2f(v.w >> 16);
  }
  float* orow = out + (size_t)t * HID + c0;
  *(float4*)orow = (float4){s[0], s[1], s[2], s[3]};
  *(float4*)(orow + 4) = (float4){s[4], s[5], s[6], s[7]};
}

extern "C" void kernel_launch(void* const* d_in, const int* in_sizes, int n_in,
                              void* d_out, int out_size, void* d_ws, size_t ws_size,
                              hipStream_t stream) {
  const float* tokens = (const float*)d_in[0];  // [4,2048,1024] f32
  const float* rw = (const float*)d_in[1];      // [16,1024] f32
  const float* rb = (const float*)d_in[2];      // [16] f32
  const float* ew = (const float*)d_in[3];      // [16,1024,1024] f32
  float* out = (float*)d_out;                   // [4,2048,1024] f32

  char* ws = (char*)d_ws;
  const size_t OFF_XB = 0;                        // 16 MB
  const size_t OFF_WT = 16777216;                 // 32 MB
  const size_t OFF_Y = 50331648;                  // 49153+ rows x 2KB (token-major)
  const size_t OFF_META = 151001088;              // = OFF_Y + 100669440
  const size_t M_TOKMAP = OFF_META + 0;           // 51200 u32
  const size_t M_GPOS = OFF_META + 204800;        // 51200 f32
  const size_t M_YDST = OFF_META + 409600;        // 51200 u32
  const size_t M_TOTAL = OFF_META + 614400;       // 1 u32 (pad 64)
  const size_t M_TABLE = OFF_META + 614464;       // 400 u32 (pad)
  const size_t M_TOPK = OFF_META + 616064;        // 8192 u32
  const size_t M_G6 = OFF_META + 648832;          // 49152 f32
  const size_t M_EPST = OFF_META + 845440;        // 8192 f32  (end ~151.9 MB)

  unsigned short* Xb = (unsigned short*)(ws + OFF_XB);
  unsigned short* Wt = (unsigned short*)(ws + OFF_WT);
  unsigned short* Y = (unsigned short*)(ws + OFF_Y);
  unsigned int* tokmap = (unsigned int*)(ws + M_TOKMAP);
  float* gpos = (float*)(ws + M_GPOS);
  unsigned int* ydst = (unsigned int*)(ws + M_YDST);
  unsigned int* total = (unsigned int*)(ws + M_TOTAL);
  unsigned int* table = (unsigned int*)(ws + M_TABLE);
  unsigned int* topk = (unsigned int*)(ws + M_TOPK);
  float* g6 = (float*)(ws + M_G6);
  float* epst = (float*)(ws + M_EPST);

  router_sparse_kernel<<<dim3(NTOK / 4), dim3(256), 0, stream>>>(
      tokens, rw, rb, Xb, topk, g6, epst);
  cvt_wt_kernel<<<dim3(HID / 64, HID / 64, NE), dim3(256), 0, stream>>>(ew, Wt);
  sortassign_kernel<<<dim3(NE), dim3(256), 0, stream>>>(
      topk, g6, tokmap, gpos, ydst, table, total);
  moe_ggemm_kernel<<<dim3(MAXBLK * 8), dim3(256), 0, stream>>>(
      Xb, Wt, table, total, tokmap, gpos, ydst, Y);
  reduce_kernel<<<dim3(NTOK / 2), dim3(256), 0, stream>>>(Y, epst, out);
}